// Round 13
// baseline (99.942 us; speedup 1.0000x reference)
//
#include <hip/hip_runtime.h>
#include <math.h>
#include <stdint.h>

#define NBUCKET 4096
#define NCOPY   8
#define CAP     16384
#define QCAP    4096
#define STAGE   4096
#define FCAP    1024
#define TOPK    100
#define NLVL    3
#define NCLS    80

#define PA_G1 1024
#define PA_G2 256
#define PA_G3 64
#define CK_G1 192
#define CK_G2 48
#define CK_G3 12

// ---------------------------------------------------------------------------
// Zero: hist (96*256*16B = 393216B) + the two last-block sync counters.
// ---------------------------------------------------------------------------
__global__ void zero_kernel(uint4* __restrict__ p, unsigned int* __restrict__ ctr)
{
    p[blockIdx.x * 256 + threadIdx.x] = make_uint4(0u, 0u, 0u, 0u);
    if (blockIdx.x == 0 && threadIdx.x == 0) { ctr[0] = 0u; ctr[1] = 0u; }
}

// ---------------------------------------------------------------------------
// Pass A: per-anchor max prob -> amax[], distributed LDS hist.
// NEW: float4 global loads staged through LDS.  Each wave handles 4 anchors
// per chunk = 320 contiguous floats = 80 float4 (64 lanes + 16).  Scalar
// consumption from LDS uses the IDENTICAL lane->value placement as before,
// so the max/sum shuffle trees see bit-identical operands in the same order.
// 2-chunk unroll: both chunks' global loads issue before either consume.
// ---------------------------------------------------------------------------
__global__ void passA_kernel(const float* __restrict__ conf1, const float* __restrict__ cls1,
                             const float* __restrict__ conf2, const float* __restrict__ cls2,
                             const float* __restrict__ conf3, const float* __restrict__ cls3,
                             int n1, int n2, int n3,
                             unsigned int* __restrict__ ghist,
                             float* __restrict__ amax)
{
    const float* conf; const float* cls; int nA, nb, b;
    unsigned int* gh; float* am;
    if (blockIdx.x < PA_G1) {
        b = blockIdx.x; conf = conf1; cls = cls1; nA = n1; nb = PA_G1;
        gh = ghist; am = amax;
    } else if (blockIdx.x < PA_G1 + PA_G2) {
        b = blockIdx.x - PA_G1; conf = conf2; cls = cls2; nA = n2; nb = PA_G2;
        gh = ghist + NCOPY * NBUCKET; am = amax + n1;
    } else {
        b = blockIdx.x - PA_G1 - PA_G2; conf = conf3; cls = cls3; nA = n3; nb = PA_G3;
        gh = ghist + 2 * NCOPY * NBUCKET; am = amax + n1 + n2;
    }

    __shared__ unsigned int sh[NBUCKET];       // 16 KB
    __shared__ float4 stg[4][2][80];           // 10 KB: wave x chunk x 80 f4
    for (int i = threadIdx.x; i < NBUCKET; i += 256) sh[i] = 0;
    __syncthreads();

    int wv   = threadIdx.x >> 6;     // wave 0..3
    int lane = threadIdx.x & 63;
    int sub  = threadIdx.x & 15;
    int g16  = threadIdx.x >> 4;     // 0..15  (= 4*wv + gloc)
    int gloc = g16 & 3;              // anchor within wave
    int nChunk = nA >> 4;

    for (int ch = b; ch < nChunk; ch += 2 * nb) {
        int ch1 = ch + nb;
        bool has1 = ch1 < nChunk;    // block-uniform

        // stage: global float4 -> LDS (this wave's 4 anchors per chunk)
        {
            const float4* src = (const float4*)(cls + (size_t)(ch * 16 + 4 * wv) * NCLS);
            stg[wv][0][lane] = src[lane];
            if (lane < 16) stg[wv][0][64 + lane] = src[64 + lane];
        }
        if (has1) {
            const float4* src = (const float4*)(cls + (size_t)(ch1 * 16 + 4 * wv) * NCLS);
            stg[wv][1][lane] = src[lane];
            if (lane < 16) stg[wv][1][64 + lane] = src[64 + lane];
        }
        int a0 = (ch << 4) + g16;
        float cv0 = conf[a0];
        int a1 = has1 ? (ch1 << 4) + g16 : 0;
        float cv1 = has1 ? conf[a1] : 0.0f;

        // consume chunk 0 (identical values/lanes/op-order as scalar version)
        {
            const float* rowl = (const float*)&stg[wv][0][0] + gloc * NCLS;
            float c0 = rowl[sub], c1 = rowl[sub + 16], c2 = rowl[sub + 32],
                  c3 = rowl[sub + 48], c4 = rowl[sub + 64];
            float sig = 1.0f / (1.0f + expf(-cv0));
            float m = fmaxf(fmaxf(fmaxf(c0, c1), fmaxf(c2, c3)), c4);
#pragma unroll
            for (int o = 8; o >= 1; o >>= 1) m = fmaxf(m, __shfl_xor(m, o, 16));
            float s = ((expf(c0 - m) + expf(c1 - m)) + (expf(c2 - m) + expf(c3 - m))) + expf(c4 - m);
#pragma unroll
            for (int o = 8; o >= 1; o >>= 1) s += __shfl_xor(s, o, 16);
            float inv = sig / s;
            if (sub == 0) {
                am[a0] = inv;
                unsigned bk = __float_as_uint(inv) >> 18;
                if (bk > NBUCKET - 1) bk = NBUCKET - 1;
                atomicAdd(&sh[bk], 1u);
            }
        }
        // consume chunk 1
        if (has1) {
            const float* rowl = (const float*)&stg[wv][1][0] + gloc * NCLS;
            float c0 = rowl[sub], c1 = rowl[sub + 16], c2 = rowl[sub + 32],
                  c3 = rowl[sub + 48], c4 = rowl[sub + 64];
            float sig = 1.0f / (1.0f + expf(-cv1));
            float m = fmaxf(fmaxf(fmaxf(c0, c1), fmaxf(c2, c3)), c4);
#pragma unroll
            for (int o = 8; o >= 1; o >>= 1) m = fmaxf(m, __shfl_xor(m, o, 16));
            float s = ((expf(c0 - m) + expf(c1 - m)) + (expf(c2 - m) + expf(c3 - m))) + expf(c4 - m);
#pragma unroll
            for (int o = 8; o >= 1; o >>= 1) s += __shfl_xor(s, o, 16);
            float inv = sig / s;
            if (sub == 0) {
                am[a1] = inv;
                unsigned bk = __float_as_uint(inv) >> 18;
                if (bk > NBUCKET - 1) bk = NBUCKET - 1;
                atomicAdd(&sh[bk], 1u);
            }
        }
    }
    __syncthreads();
    unsigned int* g = gh + (b & (NCOPY - 1)) * NBUCKET;
    for (int i = threadIdx.x; i < NBUCKET; i += 256) {
        unsigned v = sh[i];
        if (v) atomicAdd(&g[i], v);
    }
}

// ---------------------------------------------------------------------------
// Scan (unchanged): coarse threshold per level; zeroes ccount.
// ---------------------------------------------------------------------------
__global__ void scan_kernel(const unsigned int* __restrict__ ghist,
                            unsigned int* __restrict__ thresh,
                            unsigned int* __restrict__ ccount)
{
    int lvl = blockIdx.x;
    const unsigned int* h0 = ghist + lvl * NCOPY * NBUCKET;
    __shared__ unsigned int h[NBUCKET];
    __shared__ unsigned int ps[256];
    int t = threadIdx.x;
    if (t == 0) ccount[lvl] = 0;
    for (int bb = t; bb < NBUCKET; bb += 256) {
        unsigned s = 0;
        for (int c = 0; c < NCOPY; c++) s += h0[c * NBUCKET + bb];
        h[bb] = s;
    }
    __syncthreads();
    unsigned cs = 0;
#pragma unroll
    for (int i = 0; i < 16; i++) cs += h[NBUCKET - 1 - (t * 16 + i)];
    ps[t] = cs;
    __syncthreads();
    for (int o = 1; o < 256; o <<= 1) {
        unsigned v = (t >= o) ? ps[t - o] : 0u;
        __syncthreads();
        ps[t] += v;
        __syncthreads();
    }
    unsigned incl = ps[t], excl = incl - cs;
    if (excl < TOPK && incl >= TOPK) {
        unsigned cum = excl, B = 0;
        for (int i = 0; i < 16; i++) {
            int bb = NBUCKET - 1 - (t * 16 + i);
            cum += h[bb];
            if (cum >= TOPK) { B = (unsigned)bb; break; }
        }
        thresh[lvl] = B << 18;
    }
}

// ---------------------------------------------------------------------------
// Compact (unchanged).
// ---------------------------------------------------------------------------
__global__ void compact_kernel(const float* __restrict__ conf1, const float* __restrict__ cls1,
                               const float* __restrict__ conf2, const float* __restrict__ cls2,
                               const float* __restrict__ conf3, const float* __restrict__ cls3,
                               int n1, int n2, int n3,
                               const unsigned int* __restrict__ thresh,
                               const float* __restrict__ amax,
                               unsigned int* __restrict__ ccount,
                               float* __restrict__ cscore,
                               unsigned int* __restrict__ cidx)
{
    const float* conf; const float* cls; int bl, lvl; const float* am;
    if (blockIdx.x < CK_G1)              { lvl = 0; bl = blockIdx.x;               conf = conf1; cls = cls1; am = amax; }
    else if (blockIdx.x < CK_G1 + CK_G2) { lvl = 1; bl = blockIdx.x - CK_G1;       conf = conf2; cls = cls2; am = amax + n1; }
    else                                 { lvl = 2; bl = blockIdx.x - CK_G1 - CK_G2; conf = conf3; cls = cls3; am = amax + n1 + n2; }

    __shared__ int qn;
    __shared__ int queue[QCAP];
    if (threadIdx.x == 0) qn = 0;
    __syncthreads();

    unsigned T = thresh[lvl];
    int idx4 = bl * 256 + threadIdx.x;
    const float4* am4 = (const float4*)am;
    float4 v = am4[idx4];
    float vv[4] = {v.x, v.y, v.z, v.w};
#pragma unroll
    for (int j = 0; j < 4; j++) {
        if (__float_as_uint(vv[j]) >= T) {
            int p = atomicAdd(&qn, 1);
            if (p < QCAP) queue[p] = idx4 * 4 + j;
        }
    }
    __syncthreads();
    int qcnt = min(qn, QCAP);
    int grp = threadIdx.x >> 4;
    int sub = threadIdx.x & 15;
    float*        csl = cscore + lvl * CAP;
    unsigned int* cil = cidx   + lvl * CAP;
    for (int q = grp; q < qcnt; q += 16) {
        int a = queue[q];
        float cv  = conf[a];
        float sig = 1.0f / (1.0f + expf(-cv));
        const float* row = cls + (size_t)a * NCLS + sub;
        float c0 = row[0], c1 = row[16], c2 = row[32], c3 = row[48], c4 = row[64];
        float m = fmaxf(fmaxf(fmaxf(c0, c1), fmaxf(c2, c3)), c4);
#pragma unroll
        for (int o = 8; o >= 1; o >>= 1) m = fmaxf(m, __shfl_xor(m, o, 16));
        float e0 = expf(c0 - m), e1 = expf(c1 - m), e2 = expf(c2 - m),
              e3 = expf(c3 - m), e4 = expf(c4 - m);
        float s = ((e0 + e1) + (e2 + e3)) + e4;
#pragma unroll
        for (int o = 8; o >= 1; o >>= 1) s += __shfl_xor(s, o, 16);
        float inv = sig / s;
        float e[5] = {e0, e1, e2, e3, e4};
#pragma unroll
        for (int k = 0; k < 5; k++) {
            float p = e[k] * inv;
            if (e[k] == 1.0f || __float_as_uint(p) >= T) {
                unsigned pos = atomicAdd(&ccount[lvl], 1u);
                if (pos < CAP) {
                    csl[pos] = p;
                    cil[pos] = (unsigned)(a * NCLS + sub + 16 * k);
                }
            }
        }
    }
}

// ---------------------------------------------------------------------------
// readlane helpers
// ---------------------------------------------------------------------------
__device__ __forceinline__ float rlf(float x, int l)
{
    return __uint_as_float((unsigned)__builtin_amdgcn_readlane((int)__float_as_uint(x), l));
}
__device__ __forceinline__ int rli(int x, int l)
{
    return __builtin_amdgcn_readlane(x, l);
}
__device__ __forceinline__ unsigned long long rl64(unsigned long long x, int b)
{
    unsigned lo = (unsigned)__builtin_amdgcn_readlane((int)(unsigned)x, b);
    unsigned hi = (unsigned)__builtin_amdgcn_readlane((int)(unsigned)(x >> 32), b);
    return ((unsigned long long)hi << 32) | lo;
}

// ---------------------------------------------------------------------------
// Select+Prep fused: 3 blocks x 1024 (select phases at full width again;
// round-12's 320-thread version cost ~3x in the O(fn^2) rank-select).
// Last block (device atomic + fences) runs the 320-thread prep body.
// ---------------------------------------------------------------------------
__global__ __launch_bounds__(1024, 4) void select_prep_kernel(
    const float* __restrict__ cscore, const unsigned int* __restrict__ cidx,
    const unsigned int* __restrict__ ccount,
    const unsigned int* __restrict__ thresh,
    float* __restrict__ sel_sc, int* __restrict__ sel_ix,
    const float* __restrict__ reg1, const float* __restrict__ anch1,
    const float* __restrict__ reg2, const float* __restrict__ anch2,
    const float* __restrict__ reg3, const float* __restrict__ anch3,
    float* __restrict__ t_score, float* __restrict__ t_box,
    int* __restrict__ t_label, int* __restrict__ t_valid,
    unsigned int* __restrict__ sel_done)
{
    int lvl = blockIdx.x;
    int tid = threadIdx.x;
    __shared__ float        q_sc[STAGE];
    __shared__ unsigned int q_ix[STAGE];
    __shared__ unsigned int subh[4096];
    __shared__ unsigned int kthr_s;
    __shared__ int          fcnt;
    __shared__ float        f_sc[FCAP];
    __shared__ unsigned int f_ix[FCAP];
    __shared__ int          lastflag;

    int cnt = min((int)ccount[lvl], CAP);
    const float*        sc = cscore + lvl * CAP;
    const unsigned int* ix = cidx   + lvl * CAP;
    int n = min(cnt, STAGE);
    unsigned B12 = (thresh[lvl] >> 18) << 12;

    for (int i = tid; i < 4096; i += 1024) subh[i] = 0;
    if (tid == 0) fcnt = 0;
    for (int c = tid; c < n; c += 1024) { q_sc[c] = sc[c]; q_ix[c] = ix[c]; }
    if (tid < TOPK) { sel_sc[lvl * TOPK + tid] = -1e30f; sel_ix[lvl * TOPK + tid] = 0; }
    __syncthreads();

    for (int c = tid; c < cnt; c += 1024) {
        float v = (c < n) ? q_sc[c] : sc[c];
        unsigned rel = (__float_as_uint(v) >> 6) - B12;
        if (rel > 4095u) rel = 4095u;
        atomicAdd(&subh[rel], 1u);
    }
    __syncthreads();

    // descending scan by wave 0: lane l covers buckets [4095-64l .. 4032-64l]
    if (tid < 64) {
        int base = 4095 - (tid << 6);
        unsigned csum = 0;
        for (int i = 0; i < 64; i++) csum += subh[base - i];
        unsigned v = csum;
        for (int o = 1; o < 64; o <<= 1) {
            unsigned u = __shfl_up(v, o);
            if (tid >= o) v += u;
        }
        unsigned excl = v - csum;
        if (excl < TOPK && v >= TOPK) {
            unsigned cum = excl;
            for (int i = 0; i < 64; i++) {
                int bb = base - i;
                cum += subh[bb];
                if (cum >= TOPK) { kthr_s = (B12 + (unsigned)bb) << 6; break; }
            }
        }
    }
    __syncthreads();
    unsigned kthr = kthr_s;

    for (int c = tid; c < cnt; c += 1024) {
        float v; unsigned vi;
        if (c < n) { v = q_sc[c]; vi = q_ix[c]; }
        else       { v = sc[c];   vi = ix[c];   }
        if (__float_as_uint(v) >= kthr) {
            int p = atomicAdd(&fcnt, 1);
            if (p < FCAP) { f_sc[p] = v; f_ix[p] = vi; }
        }
    }
    __syncthreads();
    int fn = min(fcnt, FCAP);

    for (int c = tid; c < fn; c += 1024) {
        float    my  = f_sc[c];
        unsigned myi = f_ix[c];
        int rank = 0;
        for (int k = 0; k < fn; k++) {
            float v = f_sc[k];
            rank += (v > my) || (v == my && f_ix[k] < myi);
        }
        if (rank < TOPK) {
            sel_sc[lvl * TOPK + rank] = my;
            sel_ix[lvl * TOPK + rank] = (int)myi;
        }
    }

    // ---- last-block: run prep (first 320 threads) ----
    __syncthreads();
    if (tid == 0) {
        __threadfence();
        unsigned prev = atomicAdd(sel_done, 1u);
        lastflag = (prev == NLVL - 1);
    }
    __syncthreads();
    if (!lastflag) return;
    if (tid == 0) __threadfence();
    __syncthreads();

    if (tid < 320) {
        int lane = tid & 63;
        float sg[5];
#pragma unroll
        for (int g = 0; g < 5; g++) {
            int k = g * 64 + lane;
            sg[g] = (k < 300) ? sel_sc[k] : -INFINITY;
        }
        float my = (tid < 300) ? sel_sc[tid] : -INFINITY;
        int rank = 0;
#pragma unroll
        for (int g = 0; g < 5; g++) {
            int base = g * 64;
#pragma unroll 1
            for (int ii = 0; ii < 64; ii++) {
                float v = rlf(sg[g], ii);
                int k = base + ii;
                rank += (v > my) || (v == my && k < tid);
            }
        }
        if (tid < 300) {
            int lv = tid / TOPK;
            const float* reg = lv == 0 ? reg1 : (lv == 1 ? reg2 : reg3);
            const float* anc = lv == 0 ? anch1 : (lv == 1 ? anch2 : anch3);
            float stride = lv == 0 ? 8.0f : (lv == 1 ? 16.0f : 32.0f);
            int  idx = sel_ix[tid];
            int a   = idx / NCLS;
            int lab = idx % NCLS;
            float r0 = reg[4 * a + 0], r1 = reg[4 * a + 1], r2 = reg[4 * a + 2], r3 = reg[4 * a + 3];
            float a0 = anc[4 * a + 0], a1 = anc[4 * a + 1], a2 = anc[4 * a + 2], a3 = anc[4 * a + 3];
            float cx = (1.0f / (1.0f + expf(-r0)) + a0) * stride;
            float cy = (1.0f / (1.0f + expf(-r1)) + a1) * stride;
            float w  = expf(r2) * a2;
            float h  = expf(r3) * a3;
            t_score[rank]       = my;
            t_box[4 * rank + 0] = cx - 0.5f * w;
            t_box[4 * rank + 1] = cy - 0.5f * h;
            t_box[4 * rank + 2] = cx + 0.5f * w;
            t_box[4 * rank + 3] = cy + 0.5f * h;
            t_label[rank] = lab;
            t_valid[rank] = my > 0.001f;
        }
    }
}

// ---------------------------------------------------------------------------
// Sup+NMS fused: 15 blocks x 320; last block runs the sparse serial NMS +
// output write (wave 0).
// ---------------------------------------------------------------------------
__global__ __launch_bounds__(320) void supnms_kernel(
    const float* __restrict__ t_score, const float* __restrict__ t_box,
    const int* __restrict__ t_label, const int* __restrict__ t_valid,
    unsigned long long* __restrict__ sup_ws,
    unsigned int* __restrict__ sup_done,
    float* __restrict__ out)
{
    int tid  = threadIdx.x;
    int lane = tid & 63;
    int w    = tid >> 6;
    int rbase = 20 * blockIdx.x;
    __shared__ int lastflag;

    float bx1 = 0, by1 = 0, bx2 = 0, by2 = 0, areaj = 0;
    int labj = -1;
    if (tid < 300) {
        bx1 = t_box[4 * tid + 0]; by1 = t_box[4 * tid + 1];
        bx2 = t_box[4 * tid + 2]; by2 = t_box[4 * tid + 3];
        labj = t_label[tid];
        areaj = (bx2 - bx1) * (by2 - by1);
    }

    float rx1 = 0, ry1 = 0, rx2 = 0, ry2 = 0, rar = 1.0f;
    int rlab = -9;
    int r = rbase + lane;
    if (lane < 20 && r < 300) {
        rx1 = t_box[4 * r + 0]; ry1 = t_box[4 * r + 1];
        rx2 = t_box[4 * r + 2]; ry2 = t_box[4 * r + 3];
        rar = (rx2 - rx1) * (ry2 - ry1);
        rlab = t_label[r];
    }

#pragma unroll 1
    for (int ii = 0; ii < 20; ii++) {
        int i = rbase + ii;
        float xi1 = rlf(rx1, ii), yi1 = rlf(ry1, ii);
        float xi2 = rlf(rx2, ii), yi2 = rlf(ry2, ii);
        float ari = rlf(rar, ii);
        int  labi = rli(rlab, ii);
        float xx1 = fmaxf(xi1, bx1), yy1 = fmaxf(yi1, by1);
        float xx2 = fminf(xi2, bx2), yy2 = fminf(yi2, by2);
        float ww = fmaxf(1e-10f, xx2 - xx1);
        float hh = fmaxf(1e-10f, yy2 - yy1);
        float inter = ww * hh;
        float iou = inter / (ari + areaj - inter);
        bool p = (tid > i) && (labj == labi) && (iou > 0.5f) && (tid < 300);
        unsigned long long m = __ballot(p);
        if (lane == 0) sup_ws[i * 5 + w] = m;
    }

    __syncthreads();
    if (tid == 0) {
        __threadfence();
        unsigned prev = atomicAdd(sup_done, 1u);
        lastflag = (prev == 14);
    }
    __syncthreads();
    if (!lastflag) return;
    if (tid == 0) __threadfence();
    __syncthreads();

    if (tid < 64) {
        unsigned long long s0[5], s1[5], s2[5], s3[5], s4[5];
#pragma unroll
        for (int q = 0; q < 5; q++) {
            s0[q] = sup_ws[(lane)       * 5 + q];
            s1[q] = sup_ws[(lane + 64)  * 5 + q];
            s2[q] = sup_ws[(lane + 128) * 5 + q];
            s3[q] = sup_ws[(lane + 192) * 5 + q];
            s4[q] = (lane + 256 < 300) ? sup_ws[(lane + 256) * 5 + q] : 0ull;
        }

        unsigned long long k0 = __ballot(t_valid[lane] != 0);
        unsigned long long k1 = __ballot(t_valid[lane + 64] != 0);
        unsigned long long k2 = __ballot(t_valid[lane + 128] != 0);
        unsigned long long k3 = __ballot(t_valid[lane + 192] != 0);
        unsigned long long k4 = __ballot((lane + 256 < 300) ? (t_valid[lane + 256] != 0) : false);

        unsigned long long nz0 = __ballot((s0[0] | s0[1] | s0[2] | s0[3] | s0[4]) != 0ull);
        unsigned long long nz1 = __ballot((s1[0] | s1[1] | s1[2] | s1[3] | s1[4]) != 0ull);
        unsigned long long nz2 = __ballot((s2[0] | s2[1] | s2[2] | s2[3] | s2[4]) != 0ull);
        unsigned long long nz3 = __ballot((s3[0] | s3[1] | s3[2] | s3[3] | s3[4]) != 0ull);
        unsigned long long nz4 = __ballot((s4[0] | s4[1] | s4[2] | s4[3] | s4[4]) != 0ull);

#define NMS_SPARSE(SR, KR, NZ)                                                \
        {                                                                     \
            unsigned long long m = (NZ);                                      \
            while (m) {                                                       \
                int b = __builtin_ctzll(m);                                   \
                m &= m - 1ull;                                                \
                if ((KR >> b) & 1ull) {                                       \
                    k0 &= ~rl64(SR[0], b);                                    \
                    k1 &= ~rl64(SR[1], b);                                    \
                    k2 &= ~rl64(SR[2], b);                                    \
                    k3 &= ~rl64(SR[3], b);                                    \
                    k4 &= ~rl64(SR[4], b);                                    \
                }                                                             \
            }                                                                 \
        }
        NMS_SPARSE(s0, k0, nz0)
        NMS_SPARSE(s1, k1, nz1)
        NMS_SPARSE(s2, k2, nz2)
        NMS_SPARSE(s3, k3, nz3)
        NMS_SPARSE(s4, k4, nz4)
#undef NMS_SPARSE

#pragma unroll 1
        for (int e = lane; e < 300 * 6; e += 64) {
            int row = e / 6, col = e % 6;
            unsigned long long kw = (row < 64) ? k0 : (row < 128) ? k1 : (row < 192) ? k2
                                  : (row < 256) ? k3 : k4;
            bool kept = (kw >> (row & 63)) & 1ull;
            float v = 0.0f;
            if (kept) {
                if (col < 4) {
                    v = t_box[4 * row + col] * (1.0f / 2048.0f);
                    v = fminf(fmaxf(v, 0.0f), 1.0f);
                } else if (col == 4) {
                    v = t_score[row];
                } else {
                    v = (float)t_label[row];
                }
            }
            out[e] = v;
        }
    }
}

// ---------------------------------------------------------------------------
extern "C" void kernel_launch(void* const* d_in, const int* in_sizes, int n_in,
                              void* d_out, int out_size, void* d_ws, size_t ws_size,
                              hipStream_t stream)
{
    const float* conf1 = (const float*)d_in[0];
    const float* cls1  = (const float*)d_in[1];
    const float* reg1  = (const float*)d_in[2];
    const float* anch1 = (const float*)d_in[3];
    const float* conf2 = (const float*)d_in[4];
    const float* cls2  = (const float*)d_in[5];
    const float* reg2  = (const float*)d_in[6];
    const float* anch2 = (const float*)d_in[7];
    const float* conf3 = (const float*)d_in[8];
    const float* cls3  = (const float*)d_in[9];
    const float* reg3  = (const float*)d_in[10];
    const float* anch3 = (const float*)d_in[11];

    int N1 = in_sizes[0];   // 196608
    int N2 = in_sizes[4];   // 49152
    int N3 = in_sizes[8];   // 12288

    unsigned int* wsu    = (unsigned int*)d_ws;
    unsigned int* hist   = wsu;                               // [3][NCOPY][NBUCKET]
    unsigned int* thresh = wsu + NLVL * NCOPY * NBUCKET;      // [3]
    unsigned int* ccount = thresh + NLVL;                     // [3]
    unsigned int* ctrs   = thresh + 6;                        // [2]: sel_done, sup_done
    float*        amax   = (float*)(wsu + NLVL * NCOPY * NBUCKET + 16);   // [N1+N2+N3]
    float*        cscore = amax + (N1 + N2 + N3);                         // [3][CAP]
    unsigned int* cidx   = (unsigned int*)(cscore + NLVL * CAP);          // [3][CAP]
    float*        sel_sc = (float*)(cidx + NLVL * CAP);                   // [300]
    int*          sel_ix = (int*)(sel_sc + NLVL * TOPK);                  // [300]
    float*        t_score = (float*)(sel_ix + NLVL * TOPK);               // [300]
    float*        t_box   = t_score + 300;                                // [300*4]
    int*          t_label = (int*)(t_box + 1200);                         // [300]
    int*          t_valid = t_label + 300;                                // [300]
    unsigned long long* sup_ws =
        (unsigned long long*)(((uintptr_t)(t_valid + 300) + 15) & ~(uintptr_t)15); // [300*5]

    zero_kernel<<<96, 256, 0, stream>>>((uint4*)hist, ctrs);

    passA_kernel<<<PA_G1 + PA_G2 + PA_G3, 256, 0, stream>>>(
        conf1, cls1, conf2, cls2, conf3, cls3, N1, N2, N3, hist, amax);

    scan_kernel<<<NLVL, 256, 0, stream>>>(hist, thresh, ccount);

    compact_kernel<<<CK_G1 + CK_G2 + CK_G3, 256, 0, stream>>>(
        conf1, cls1, conf2, cls2, conf3, cls3, N1, N2, N3,
        thresh, amax, ccount, cscore, cidx);

    select_prep_kernel<<<NLVL, 1024, 0, stream>>>(
        cscore, cidx, ccount, thresh, sel_sc, sel_ix,
        reg1, anch1, reg2, anch2, reg3, anch3,
        t_score, t_box, t_label, t_valid, &ctrs[0]);

    supnms_kernel<<<15, 320, 0, stream>>>(
        t_score, t_box, t_label, t_valid, sup_ws, &ctrs[1], (float*)d_out);
}

// Round 14
// 88.099 us; speedup vs baseline: 1.1344x; 1.1344x over previous
//
#include <hip/hip_runtime.h>
#include <math.h>
#include <stdint.h>

#define NBUCKET 4096
#define NCOPY   8
#define CAP     16384
#define QCAP    4096
#define STAGE   4096
#define FCAP    1024
#define TOPK    100
#define NLVL    3
#define NCLS    80

#define PA_G1 2048
#define PA_G2 512
#define PA_G3 128
#define CK_G1 192
#define CK_G2 48
#define CK_G3 12

// ---------------------------------------------------------------------------
// Zero: hist (96*256*16B = 393216B).
// ---------------------------------------------------------------------------
__global__ void zero_kernel(uint4* __restrict__ p)
{
    p[blockIdx.x * 256 + threadIdx.x] = make_uint4(0u, 0u, 0u, 0u);
}

// ---------------------------------------------------------------------------
// Pass A: per-anchor max prob -> amax[], distributed LDS hist -> NCOPY global
// copies.  4-deep chunk unroll, scalar loads (no LDS staging — r13 showed the
// stage->read round-trip adds a dependent chain).  All 4 chunks' loads issue
// before any consume: 24 VMEM in flight/wave.  Grid x2 vs r11 for 2x TLP.
// Numerics bit-identical to r11 (same 16-lane groups, same shuffle trees).
// ---------------------------------------------------------------------------
__global__ void passA_kernel(const float* __restrict__ conf1, const float* __restrict__ cls1,
                             const float* __restrict__ conf2, const float* __restrict__ cls2,
                             const float* __restrict__ conf3, const float* __restrict__ cls3,
                             int n1, int n2, int n3,
                             unsigned int* __restrict__ ghist,
                             float* __restrict__ amax)
{
    const float* conf; const float* cls; int nA, nb, b;
    unsigned int* gh; float* am;
    if (blockIdx.x < PA_G1) {
        b = blockIdx.x; conf = conf1; cls = cls1; nA = n1; nb = PA_G1;
        gh = ghist; am = amax;
    } else if (blockIdx.x < PA_G1 + PA_G2) {
        b = blockIdx.x - PA_G1; conf = conf2; cls = cls2; nA = n2; nb = PA_G2;
        gh = ghist + NCOPY * NBUCKET; am = amax + n1;
    } else {
        b = blockIdx.x - PA_G1 - PA_G2; conf = conf3; cls = cls3; nA = n3; nb = PA_G3;
        gh = ghist + 2 * NCOPY * NBUCKET; am = amax + n1 + n2;
    }

    __shared__ unsigned int sh[NBUCKET];
    for (int i = threadIdx.x; i < NBUCKET; i += 256) sh[i] = 0;
    __syncthreads();

    int sub = threadIdx.x & 15;
    int g16 = threadIdx.x >> 4;
    int nChunk = nA >> 4;

    for (int ch = b; ch < nChunk; ch += 4 * nb) {
        bool has[4];
        int  aa[4];
        float cv[4];
        float c[4][5];
#pragma unroll
        for (int u = 0; u < 4; u++) {
            int chu = ch + u * nb;
            has[u] = chu < nChunk;          // block-uniform
            aa[u]  = (chu << 4) + g16;
        }
        // issue all loads up front (up to 24 VMEM in flight)
#pragma unroll
        for (int u = 0; u < 4; u++) {
            if (has[u]) {
                cv[u] = conf[aa[u]];
                const float* row = cls + (size_t)aa[u] * NCLS + sub;
                c[u][0] = row[0];
                c[u][1] = row[16];
                c[u][2] = row[32];
                c[u][3] = row[48];
                c[u][4] = row[64];
            }
        }
        // consume (identical math/op-order per anchor as r11)
#pragma unroll
        for (int u = 0; u < 4; u++) {
            if (has[u]) {
                float sig = 1.0f / (1.0f + expf(-cv[u]));
                float m = fmaxf(fmaxf(fmaxf(c[u][0], c[u][1]), fmaxf(c[u][2], c[u][3])), c[u][4]);
#pragma unroll
                for (int o = 8; o >= 1; o >>= 1) m = fmaxf(m, __shfl_xor(m, o, 16));
                float s = ((expf(c[u][0] - m) + expf(c[u][1] - m)) +
                           (expf(c[u][2] - m) + expf(c[u][3] - m))) + expf(c[u][4] - m);
#pragma unroll
                for (int o = 8; o >= 1; o >>= 1) s += __shfl_xor(s, o, 16);
                float inv = sig / s;         // == max over the 80 probs, exactly
                if (sub == 0) {
                    am[aa[u]] = inv;
                    unsigned bk = __float_as_uint(inv) >> 18;
                    if (bk > NBUCKET - 1) bk = NBUCKET - 1;
                    atomicAdd(&sh[bk], 1u);
                }
            }
        }
    }
    __syncthreads();
    unsigned int* g = gh + (b & (NCOPY - 1)) * NBUCKET;
    for (int i = threadIdx.x; i < NBUCKET; i += 256) {
        unsigned v = sh[i];
        if (v) atomicAdd(&g[i], v);
    }
}

// ---------------------------------------------------------------------------
// Scan: per level, smallest bucket B with count-above >= TOPK; T = B<<18.
// Also zeroes ccount for compact.
// ---------------------------------------------------------------------------
__global__ void scan_kernel(const unsigned int* __restrict__ ghist,
                            unsigned int* __restrict__ thresh,
                            unsigned int* __restrict__ ccount)
{
    int lvl = blockIdx.x;
    const unsigned int* h0 = ghist + lvl * NCOPY * NBUCKET;
    __shared__ unsigned int h[NBUCKET];
    __shared__ unsigned int ps[256];
    int t = threadIdx.x;
    if (t == 0) ccount[lvl] = 0;
    for (int bb = t; bb < NBUCKET; bb += 256) {
        unsigned s = 0;
        for (int c = 0; c < NCOPY; c++) s += h0[c * NBUCKET + bb];
        h[bb] = s;
    }
    __syncthreads();
    unsigned cs = 0;
#pragma unroll
    for (int i = 0; i < 16; i++) cs += h[NBUCKET - 1 - (t * 16 + i)];
    ps[t] = cs;
    __syncthreads();
    for (int o = 1; o < 256; o <<= 1) {
        unsigned v = (t >= o) ? ps[t - o] : 0u;
        __syncthreads();
        ps[t] += v;
        __syncthreads();
    }
    unsigned incl = ps[t], excl = incl - cs;
    if (excl < TOPK && incl >= TOPK) {
        unsigned cum = excl, B = 0;
        for (int i = 0; i < 16; i++) {
            int bb = NBUCKET - 1 - (t * 16 + i);
            cum += h[bb];
            if (cum >= TOPK) { B = (unsigned)bb; break; }
        }
        thresh[lvl] = B << 18;
    }
}

// ---------------------------------------------------------------------------
// Compact: scan amax (float4), queue anchors >= T in LDS, recompute their
// probs, emit class-scores >= T (max class unconditional).
// ---------------------------------------------------------------------------
__global__ void compact_kernel(const float* __restrict__ conf1, const float* __restrict__ cls1,
                               const float* __restrict__ conf2, const float* __restrict__ cls2,
                               const float* __restrict__ conf3, const float* __restrict__ cls3,
                               int n1, int n2, int n3,
                               const unsigned int* __restrict__ thresh,
                               const float* __restrict__ amax,
                               unsigned int* __restrict__ ccount,
                               float* __restrict__ cscore,
                               unsigned int* __restrict__ cidx)
{
    const float* conf; const float* cls; int bl, lvl; const float* am;
    if (blockIdx.x < CK_G1)              { lvl = 0; bl = blockIdx.x;               conf = conf1; cls = cls1; am = amax; }
    else if (blockIdx.x < CK_G1 + CK_G2) { lvl = 1; bl = blockIdx.x - CK_G1;       conf = conf2; cls = cls2; am = amax + n1; }
    else                                 { lvl = 2; bl = blockIdx.x - CK_G1 - CK_G2; conf = conf3; cls = cls3; am = amax + n1 + n2; }

    __shared__ int qn;
    __shared__ int queue[QCAP];
    if (threadIdx.x == 0) qn = 0;
    __syncthreads();

    unsigned T = thresh[lvl];
    int idx4 = bl * 256 + threadIdx.x;
    const float4* am4 = (const float4*)am;
    float4 v = am4[idx4];
    float vv[4] = {v.x, v.y, v.z, v.w};
#pragma unroll
    for (int j = 0; j < 4; j++) {
        if (__float_as_uint(vv[j]) >= T) {
            int p = atomicAdd(&qn, 1);
            if (p < QCAP) queue[p] = idx4 * 4 + j;
        }
    }
    __syncthreads();
    int qcnt = min(qn, QCAP);
    int grp = threadIdx.x >> 4;
    int sub = threadIdx.x & 15;
    float*        csl = cscore + lvl * CAP;
    unsigned int* cil = cidx   + lvl * CAP;
    for (int q = grp; q < qcnt; q += 16) {
        int a = queue[q];
        float cv  = conf[a];
        float sig = 1.0f / (1.0f + expf(-cv));
        const float* row = cls + (size_t)a * NCLS + sub;
        float c0 = row[0], c1 = row[16], c2 = row[32], c3 = row[48], c4 = row[64];
        float m = fmaxf(fmaxf(fmaxf(c0, c1), fmaxf(c2, c3)), c4);
#pragma unroll
        for (int o = 8; o >= 1; o >>= 1) m = fmaxf(m, __shfl_xor(m, o, 16));
        float e0 = expf(c0 - m), e1 = expf(c1 - m), e2 = expf(c2 - m),
              e3 = expf(c3 - m), e4 = expf(c4 - m);
        float s = ((e0 + e1) + (e2 + e3)) + e4;
#pragma unroll
        for (int o = 8; o >= 1; o >>= 1) s += __shfl_xor(s, o, 16);
        float inv = sig / s;
        float e[5] = {e0, e1, e2, e3, e4};
#pragma unroll
        for (int k = 0; k < 5; k++) {
            float p = e[k] * inv;
            if (e[k] == 1.0f || __float_as_uint(p) >= T) {
                unsigned pos = atomicAdd(&ccount[lvl], 1u);
                if (pos < CAP) {
                    csl[pos] = p;
                    cil[pos] = (unsigned)(a * NCLS + sub + 16 * k);
                }
            }
        }
    }
}

// ---------------------------------------------------------------------------
// Select: one block per level — stage, sub-hist refine, filter, exact
// rank-select (score desc, idx asc).  (r11 form, 1024 threads.)
// ---------------------------------------------------------------------------
__global__ __launch_bounds__(1024, 4) void select_kernel(
    const float* __restrict__ cscore, const unsigned int* __restrict__ cidx,
    const unsigned int* __restrict__ ccount,
    const unsigned int* __restrict__ thresh,
    float* __restrict__ sel_sc, int* __restrict__ sel_ix)
{
    int lvl = blockIdx.x;
    int tid = threadIdx.x;
    __shared__ float        q_sc[STAGE];
    __shared__ unsigned int q_ix[STAGE];
    __shared__ unsigned int subh[4096];
    __shared__ unsigned int ps[1024];
    __shared__ unsigned int kthr_s;
    __shared__ int          fcnt;
    __shared__ float        f_sc[FCAP];
    __shared__ unsigned int f_ix[FCAP];

    int cnt = min((int)ccount[lvl], CAP);
    const float*        sc = cscore + lvl * CAP;
    const unsigned int* ix = cidx   + lvl * CAP;
    int n = min(cnt, STAGE);
    unsigned B12 = (thresh[lvl] >> 18) << 12;

    for (int i = tid; i < 4096; i += 1024) subh[i] = 0;
    if (tid == 0) fcnt = 0;
    for (int c = tid; c < n; c += 1024) { q_sc[c] = sc[c]; q_ix[c] = ix[c]; }
    if (tid < TOPK) { sel_sc[lvl * TOPK + tid] = -1e30f; sel_ix[lvl * TOPK + tid] = 0; }
    __syncthreads();

    for (int c = tid; c < cnt; c += 1024) {
        float v = (c < n) ? q_sc[c] : sc[c];
        unsigned rel = (__float_as_uint(v) >> 6) - B12;
        if (rel > 4095u) rel = 4095u;
        atomicAdd(&subh[rel], 1u);
    }
    __syncthreads();

    unsigned cs = 0;
#pragma unroll
    for (int i = 0; i < 4; i++) cs += subh[4095 - 4 * tid - i];
    ps[tid] = cs;
    __syncthreads();
    for (int o = 1; o < 1024; o <<= 1) {
        unsigned v = (tid >= o) ? ps[tid - o] : 0u;
        __syncthreads();
        ps[tid] += v;
        __syncthreads();
    }
    {
        unsigned incl = ps[tid], excl = incl - cs;
        if (excl < TOPK && incl >= TOPK) {
            unsigned cum = excl;
            for (int i = 0; i < 4; i++) {
                int sb = 4095 - 4 * tid - i;
                cum += subh[sb];
                if (cum >= TOPK) { kthr_s = (B12 + (unsigned)sb) << 6; break; }
            }
        }
    }
    __syncthreads();
    unsigned kthr = kthr_s;

    for (int c = tid; c < cnt; c += 1024) {
        float v; unsigned vi;
        if (c < n) { v = q_sc[c]; vi = q_ix[c]; }
        else       { v = sc[c];   vi = ix[c];   }
        if (__float_as_uint(v) >= kthr) {
            int p = atomicAdd(&fcnt, 1);
            if (p < FCAP) { f_sc[p] = v; f_ix[p] = vi; }
        }
    }
    __syncthreads();
    int fn = min(fcnt, FCAP);

    for (int c = tid; c < fn; c += 1024) {
        float    my  = f_sc[c];
        unsigned myi = f_ix[c];
        int rank = 0;
        for (int k = 0; k < fn; k++) {
            float v = f_sc[k];
            rank += (v > my) || (v == my && f_ix[k] < myi);
        }
        if (rank < TOPK) {
            sel_sc[lvl * TOPK + rank] = my;
            sel_ix[lvl * TOPK + rank] = (int)myi;
        }
    }
}

// ---------------------------------------------------------------------------
// readlane helpers
// ---------------------------------------------------------------------------
__device__ __forceinline__ float rlf(float x, int l)
{
    return __uint_as_float((unsigned)__builtin_amdgcn_readlane((int)__float_as_uint(x), l));
}
__device__ __forceinline__ int rli(int x, int l)
{
    return __builtin_amdgcn_readlane(x, l);
}
__device__ __forceinline__ unsigned long long rl64(unsigned long long x, int b)
{
    unsigned lo = (unsigned)__builtin_amdgcn_readlane((int)(unsigned)x, b);
    unsigned hi = (unsigned)__builtin_amdgcn_readlane((int)(unsigned)(x >> 32), b);
    return ((unsigned long long)hi << 32) | lo;
}

// ---------------------------------------------------------------------------
// Prep: 1 x 320.  Decode + stable rank-sort (registers + readlane).
// ---------------------------------------------------------------------------
__global__ void prep_kernel(
    const float* __restrict__ reg1, const float* __restrict__ anch1,
    const float* __restrict__ reg2, const float* __restrict__ anch2,
    const float* __restrict__ reg3, const float* __restrict__ anch3,
    const float* __restrict__ sel_sc, const int* __restrict__ sel_ix,
    float* __restrict__ t_score, float* __restrict__ t_box,
    int* __restrict__ t_label, int* __restrict__ t_valid)
{
    int tid  = threadIdx.x;
    int lane = tid & 63;

    float sg[5];
#pragma unroll
    for (int g = 0; g < 5; g++) {
        int k = g * 64 + lane;
        sg[g] = (k < 300) ? sel_sc[k] : -INFINITY;
    }

    float my = (tid < 300) ? sel_sc[tid] : -INFINITY;
    int rank = 0;
#pragma unroll
    for (int g = 0; g < 5; g++) {
        int base = g * 64;
#pragma unroll 1
        for (int ii = 0; ii < 64; ii++) {
            float v = rlf(sg[g], ii);
            int k = base + ii;
            rank += (v > my) || (v == my && k < tid);
        }
    }

    if (tid < 300) {
        int lvl = tid / TOPK;
        const float* reg = lvl == 0 ? reg1 : (lvl == 1 ? reg2 : reg3);
        const float* anc = lvl == 0 ? anch1 : (lvl == 1 ? anch2 : anch3);
        float stride = lvl == 0 ? 8.0f : (lvl == 1 ? 16.0f : 32.0f);
        int  idx = sel_ix[tid];
        int a   = idx / NCLS;
        int lab = idx % NCLS;
        float r0 = reg[4 * a + 0], r1 = reg[4 * a + 1], r2 = reg[4 * a + 2], r3 = reg[4 * a + 3];
        float a0 = anc[4 * a + 0], a1 = anc[4 * a + 1], a2 = anc[4 * a + 2], a3 = anc[4 * a + 3];
        float cx = (1.0f / (1.0f + expf(-r0)) + a0) * stride;
        float cy = (1.0f / (1.0f + expf(-r1)) + a1) * stride;
        float w  = expf(r2) * a2;
        float h  = expf(r3) * a3;
        t_score[rank]       = my;
        t_box[4 * rank + 0] = cx - 0.5f * w;
        t_box[4 * rank + 1] = cy - 0.5f * h;
        t_box[4 * rank + 2] = cx + 0.5f * w;
        t_box[4 * rank + 3] = cy + 0.5f * h;
        t_label[rank] = lab;
        t_valid[rank] = my > 0.001f;
    }
}

// ---------------------------------------------------------------------------
// Sup: 15 blocks x 320.  Rows [20b, 20b+20) of the 300x5 suppression matrix.
// ---------------------------------------------------------------------------
__global__ void sup_kernel(const float* __restrict__ t_box,
                           const int* __restrict__ t_label,
                           unsigned long long* __restrict__ sup_ws)
{
    int tid  = threadIdx.x;
    int lane = tid & 63;
    int w    = tid >> 6;
    int rbase = 20 * blockIdx.x;

    float bx1 = 0, by1 = 0, bx2 = 0, by2 = 0, areaj = 0;
    int labj = -1;
    if (tid < 300) {
        bx1 = t_box[4 * tid + 0]; by1 = t_box[4 * tid + 1];
        bx2 = t_box[4 * tid + 2]; by2 = t_box[4 * tid + 3];
        labj = t_label[tid];
        areaj = (bx2 - bx1) * (by2 - by1);
    }

    float rx1 = 0, ry1 = 0, rx2 = 0, ry2 = 0, rar = 1.0f;
    int rlab = -9;
    int r = rbase + lane;
    if (lane < 20 && r < 300) {
        rx1 = t_box[4 * r + 0]; ry1 = t_box[4 * r + 1];
        rx2 = t_box[4 * r + 2]; ry2 = t_box[4 * r + 3];
        rar = (rx2 - rx1) * (ry2 - ry1);
        rlab = t_label[r];
    }

#pragma unroll 1
    for (int ii = 0; ii < 20; ii++) {
        int i = rbase + ii;
        float xi1 = rlf(rx1, ii), yi1 = rlf(ry1, ii);
        float xi2 = rlf(rx2, ii), yi2 = rlf(ry2, ii);
        float ari = rlf(rar, ii);
        int  labi = rli(rlab, ii);
        float xx1 = fmaxf(xi1, bx1), yy1 = fmaxf(yi1, by1);
        float xx2 = fminf(xi2, bx2), yy2 = fminf(yi2, by2);
        float ww = fmaxf(1e-10f, xx2 - xx1);
        float hh = fmaxf(1e-10f, yy2 - yy1);
        float inter = ww * hh;
        float iou = inter / (ari + areaj - inter);
        bool p = (tid > i) && (labj == labi) && (iou > 0.5f) && (tid < 300);
        unsigned long long m = __ballot(p);
        if (lane == 0) sup_ws[i * 5 + w] = m;
    }
}

// ---------------------------------------------------------------------------
// NMS finalize: 1 x 64.  Sparse serial recurrence over nonzero rows only.
// ---------------------------------------------------------------------------
__global__ void nmsfin_kernel(const float* __restrict__ t_score,
                              const float* __restrict__ t_box,
                              const int* __restrict__ t_label,
                              const int* __restrict__ t_valid,
                              const unsigned long long* __restrict__ sup_ws,
                              float* __restrict__ out)
{
    int lane = threadIdx.x;   // 64 threads

    unsigned long long s0[5], s1[5], s2[5], s3[5], s4[5];
#pragma unroll
    for (int q = 0; q < 5; q++) {
        s0[q] = sup_ws[(lane)       * 5 + q];
        s1[q] = sup_ws[(lane + 64)  * 5 + q];
        s2[q] = sup_ws[(lane + 128) * 5 + q];
        s3[q] = sup_ws[(lane + 192) * 5 + q];
        s4[q] = (lane + 256 < 300) ? sup_ws[(lane + 256) * 5 + q] : 0ull;
    }

    unsigned long long k0 = __ballot(t_valid[lane] != 0);
    unsigned long long k1 = __ballot(t_valid[lane + 64] != 0);
    unsigned long long k2 = __ballot(t_valid[lane + 128] != 0);
    unsigned long long k3 = __ballot(t_valid[lane + 192] != 0);
    unsigned long long k4 = __ballot((lane + 256 < 300) ? (t_valid[lane + 256] != 0) : false);

    unsigned long long nz0 = __ballot((s0[0] | s0[1] | s0[2] | s0[3] | s0[4]) != 0ull);
    unsigned long long nz1 = __ballot((s1[0] | s1[1] | s1[2] | s1[3] | s1[4]) != 0ull);
    unsigned long long nz2 = __ballot((s2[0] | s2[1] | s2[2] | s2[3] | s2[4]) != 0ull);
    unsigned long long nz3 = __ballot((s3[0] | s3[1] | s3[2] | s3[3] | s3[4]) != 0ull);
    unsigned long long nz4 = __ballot((s4[0] | s4[1] | s4[2] | s4[3] | s4[4]) != 0ull);

#define NMS_SPARSE(SR, KR, NZ)                                                \
    {                                                                         \
        unsigned long long m = (NZ);                                          \
        while (m) {                                                           \
            int b = __builtin_ctzll(m);                                       \
            m &= m - 1ull;                                                    \
            if ((KR >> b) & 1ull) {                                           \
                k0 &= ~rl64(SR[0], b);                                        \
                k1 &= ~rl64(SR[1], b);                                        \
                k2 &= ~rl64(SR[2], b);                                        \
                k3 &= ~rl64(SR[3], b);                                        \
                k4 &= ~rl64(SR[4], b);                                        \
            }                                                                 \
        }                                                                     \
    }
    NMS_SPARSE(s0, k0, nz0)
    NMS_SPARSE(s1, k1, nz1)
    NMS_SPARSE(s2, k2, nz2)
    NMS_SPARSE(s3, k3, nz3)
    NMS_SPARSE(s4, k4, nz4)
#undef NMS_SPARSE

#pragma unroll 1
    for (int e = lane; e < 300 * 6; e += 64) {
        int row = e / 6, col = e % 6;
        unsigned long long kw = (row < 64) ? k0 : (row < 128) ? k1 : (row < 192) ? k2
                              : (row < 256) ? k3 : k4;
        bool kept = (kw >> (row & 63)) & 1ull;
        float v = 0.0f;
        if (kept) {
            if (col < 4) {
                v = t_box[4 * row + col] * (1.0f / 2048.0f);
                v = fminf(fmaxf(v, 0.0f), 1.0f);
            } else if (col == 4) {
                v = t_score[row];
            } else {
                v = (float)t_label[row];
            }
        }
        out[e] = v;
    }
}

// ---------------------------------------------------------------------------
extern "C" void kernel_launch(void* const* d_in, const int* in_sizes, int n_in,
                              void* d_out, int out_size, void* d_ws, size_t ws_size,
                              hipStream_t stream)
{
    const float* conf1 = (const float*)d_in[0];
    const float* cls1  = (const float*)d_in[1];
    const float* reg1  = (const float*)d_in[2];
    const float* anch1 = (const float*)d_in[3];
    const float* conf2 = (const float*)d_in[4];
    const float* cls2  = (const float*)d_in[5];
    const float* reg2  = (const float*)d_in[6];
    const float* anch2 = (const float*)d_in[7];
    const float* conf3 = (const float*)d_in[8];
    const float* cls3  = (const float*)d_in[9];
    const float* reg3  = (const float*)d_in[10];
    const float* anch3 = (const float*)d_in[11];

    int N1 = in_sizes[0];   // 196608
    int N2 = in_sizes[4];   // 49152
    int N3 = in_sizes[8];   // 12288

    unsigned int* wsu    = (unsigned int*)d_ws;
    unsigned int* hist   = wsu;                               // [3][NCOPY][NBUCKET]
    unsigned int* thresh = wsu + NLVL * NCOPY * NBUCKET;      // [3]
    unsigned int* ccount = thresh + NLVL;                     // [3]
    float*        amax   = (float*)(wsu + NLVL * NCOPY * NBUCKET + 16);   // [N1+N2+N3]
    float*        cscore = amax + (N1 + N2 + N3);                         // [3][CAP]
    unsigned int* cidx   = (unsigned int*)(cscore + NLVL * CAP);          // [3][CAP]
    float*        sel_sc = (float*)(cidx + NLVL * CAP);                   // [300]
    int*          sel_ix = (int*)(sel_sc + NLVL * TOPK);                  // [300]
    float*        t_score = (float*)(sel_ix + NLVL * TOPK);               // [300]
    float*        t_box   = t_score + 300;                                // [300*4]
    int*          t_label = (int*)(t_box + 1200);                         // [300]
    int*          t_valid = t_label + 300;                                // [300]
    unsigned long long* sup_ws =
        (unsigned long long*)(((uintptr_t)(t_valid + 300) + 15) & ~(uintptr_t)15); // [300*5]

    zero_kernel<<<96, 256, 0, stream>>>((uint4*)hist);

    passA_kernel<<<PA_G1 + PA_G2 + PA_G3, 256, 0, stream>>>(
        conf1, cls1, conf2, cls2, conf3, cls3, N1, N2, N3, hist, amax);

    scan_kernel<<<NLVL, 256, 0, stream>>>(hist, thresh, ccount);

    compact_kernel<<<CK_G1 + CK_G2 + CK_G3, 256, 0, stream>>>(
        conf1, cls1, conf2, cls2, conf3, cls3, N1, N2, N3,
        thresh, amax, ccount, cscore, cidx);

    select_kernel<<<NLVL, 1024, 0, stream>>>(cscore, cidx, ccount, thresh, sel_sc, sel_ix);

    prep_kernel<<<1, 320, 0, stream>>>(reg1, anch1, reg2, anch2, reg3, anch3,
                                       sel_sc, sel_ix, t_score, t_box, t_label, t_valid);

    sup_kernel<<<15, 320, 0, stream>>>(t_box, t_label, sup_ws);

    nmsfin_kernel<<<1, 64, 0, stream>>>(t_score, t_box, t_label, t_valid, sup_ws, (float*)d_out);
}